// Round 12
// baseline (340.536 us; speedup 1.0000x reference)
//
#include <hip/hip_runtime.h>
#include <math.h>

#define BATCH 4
#define SEQ   4096
#define DM    128
#define TOPK  64
#define SCALE 0.08838834764831845f   // 1/sqrt(128)
#define CAP   384                    // candidate cap (chunked-path select)
#define CT    160                    // fused-path expected candidates/row
#define CPAD  16                     // cntG stride in ints (64 B = 1 cacheline per row)

typedef short bf16x8 __attribute__((ext_vector_type(8)));
typedef float f32x4  __attribute__((ext_vector_type(4)));

// ---- bf16 helpers (RNE) ----
__device__ __forceinline__ unsigned short f2bf(float x) {
    unsigned u = __float_as_uint(x);
    u += 0x7FFFu + ((u >> 16) & 1u);
    return (unsigned short)(u >> 16);
}
__device__ __forceinline__ float bf2f(unsigned short h) {
    return __uint_as_float(((unsigned)h) << 16);
}
__device__ __forceinline__ void split3(float x, unsigned short& h,
                                       unsigned short& md, unsigned short& l) {
    h = f2bf(x);
    float r1 = x - bf2f(h);
    md = f2bf(r1);
    float r2 = r1 - bf2f(md);
    l = f2bf(r2);
}

__device__ __forceinline__ unsigned fmap(float f) {
    unsigned u = __float_as_uint(f);
    return (u & 0x80000000u) ? ~u : (u | 0x80000000u);
}
__device__ __forceinline__ float finv(unsigned u) {
    return (u & 0x80000000u) ? __uint_as_float(u & 0x7FFFFFFFu) : __uint_as_float(~u);
}
__device__ __forceinline__ float wave_fmax(float v) {
    #pragma unroll
    for (int m = 32; m; m >>= 1) v = fmaxf(v, __shfl_xor(v, m));
    return v;
}
__device__ __forceinline__ float wave_fsum(float v) {
    #pragma unroll
    for (int m = 32; m; m >>= 1) v += __shfl_xor(v, m);
    return v;
}
__device__ __forceinline__ unsigned wave_umax(unsigned v) {
    #pragma unroll
    for (int m = 32; m; m >>= 1) { unsigned o = __shfl_xor(v, m); v = (o > v) ? o : v; }
    return v;
}

// upper-tail normal quantile z with P(X > z) = p (Hastings, symmetric)
__device__ __forceinline__ float ztail(float p) {
    float pp = (p <= 0.5f) ? p : (1.f - p);
    float tt = sqrtf(-2.f * logf(pp));
    float z = tt - (2.30753f + 0.27061f * tt) / (1.f + 0.99229f * tt + 0.04481f * tt * tt);
    return (p <= 0.5f) ? z : -z;
}

// ---------- RoPE + 3-way bf16 decomposition + per-row threshold ----------
__global__ void rope_decomp(const float* __restrict__ q, const float* __restrict__ k,
                            unsigned short* __restrict__ qh, unsigned short* __restrict__ qm,
                            unsigned short* __restrict__ ql, unsigned short* __restrict__ kh,
                            unsigned short* __restrict__ km, unsigned short* __restrict__ kl,
                            float* __restrict__ rowT, int allN, int ct) {
    int idx = blockIdx.x * blockDim.x + threadIdx.x;
    const int total = BATCH * SEQ * (DM / 2);
    if (idx >= total) return;
    int i   = idx & 63;
    int pos = (idx >> 6) & (SEQ - 1);
    int b   = idx >> 18;
    float dv  = powf(10000.0f, (float)(2 * i) / (float)DM);
    float ang = (float)pos / dv;
    float sn, cs;
    sincosf(ang, &sn, &cs);
    size_t base = ((size_t)b * SEQ + pos) * DM + 2 * i;
    float qe = q[base], qo = q[base + 1];
    float ke = k[base], ko = k[base + 1];
    float q0 = (qe * cs - qo * sn) * SCALE, q1 = (qe * sn + qo * cs) * SCALE;
    float k0 = ke * cs - ko * sn,          k1 = ke * sn + ko * cs;
    unsigned short h, m2, l;
    split3(q0, h, m2, l); qh[base] = h;     qm[base] = m2;     ql[base] = l;
    split3(q1, h, m2, l); qh[base + 1] = h; qm[base + 1] = m2; ql[base + 1] = l;
    split3(k0, h, m2, l); kh[base] = h;     km[base] = m2;     kl[base] = l;
    split3(k1, h, m2, l); kh[base + 1] = h; km[base + 1] = m2; kl[base + 1] = l;

    // per-row candidate threshold: logits | q are iid N(0, (|q|*SCALE)^2)
    float s2 = wave_fsum(qe * qe + qo * qo);      // 64 lanes == one row
    if (i == 0) {
        int n = pos + 1;
        float T;
        if (n <= allN) T = -3.0e38f;              // take all causal cols
        else           T = sqrtf(s2) * SCALE * ztail((float)ct / (float)n);
        rowT[(b << 12) + pos] = T;
    }
}

// ---------- FUSED: one block per 128x128 tile, direct-global MFMA loop ----------
// Extraction: LDS per-row counts -> 1 padded global atomic per block-row -> writes.
__launch_bounds__(256, 3)
__global__ void topk_fused(const unsigned short* __restrict__ qh, const unsigned short* __restrict__ qm,
                           const unsigned short* __restrict__ ql, const unsigned short* __restrict__ kh,
                           const unsigned short* __restrict__ km, const unsigned short* __restrict__ kl,
                           const float* __restrict__ rowT,
                           unsigned long long* __restrict__ cand, int* __restrict__ cntG, int ch) {
    const int st = blockIdx.x, qt = blockIdx.y, b = blockIdx.z;
    if (st > qt) return;
    const int Q0 = qt * 128, S0 = st * 128;

    __shared__ int cntL[128];
    __shared__ int baseL[128];

    const int tid = threadIdx.x, lane = tid & 63, w = tid >> 6;
    const int wm = (w >> 1) * 64, wn = (w & 1) * 64;
    const bool active = (S0 + wn <= Q0 + wm + 63);

    const int rA = Q0 + wm + (lane & 15);
    const int rB = S0 + wn + (lane & 15);
    const int dc = (lane >> 4) * 8;

    f32x4 acc[4][4] = {};
    if (active) {
        #pragma unroll
        for (int kk = 0; kk < 4; ++kk) {
            const int doff = kk * 32 + dc;
            bf16x8 Ah[4], Am[4], Al[4], Bh[4], Bm[4], Bl[4];
            #pragma unroll
            for (int i = 0; i < 4; ++i) {
                size_t qoff = ((size_t)b * SEQ + rA + i * 16) * DM + doff;
                Ah[i] = *(const bf16x8*)(qh + qoff);
                Am[i] = *(const bf16x8*)(qm + qoff);
                Al[i] = *(const bf16x8*)(ql + qoff);
                size_t koff = ((size_t)b * SEQ + rB + i * 16) * DM + doff;
                Bh[i] = *(const bf16x8*)(kh + koff);
                Bm[i] = *(const bf16x8*)(km + koff);
                Bl[i] = *(const bf16x8*)(kl + koff);
            }
            #pragma unroll
            for (int i = 0; i < 4; ++i)
                #pragma unroll
                for (int j = 0; j < 4; ++j) {
                    f32x4 c = acc[i][j];
                    c = __builtin_amdgcn_mfma_f32_16x16x32_bf16(Ah[i], Bh[j], c, 0, 0, 0);
                    c = __builtin_amdgcn_mfma_f32_16x16x32_bf16(Ah[i], Bm[j], c, 0, 0, 0);
                    c = __builtin_amdgcn_mfma_f32_16x16x32_bf16(Am[i], Bh[j], c, 0, 0, 0);
                    c = __builtin_amdgcn_mfma_f32_16x16x32_bf16(Ah[i], Bl[j], c, 0, 0, 0);
                    c = __builtin_amdgcn_mfma_f32_16x16x32_bf16(Al[i], Bh[j], c, 0, 0, 0);
                    c = __builtin_amdgcn_mfma_f32_16x16x32_bf16(Am[i], Bm[j], c, 0, 0, 0);
                    acc[i][j] = c;
                }
        }
    }

    // ---- extraction. C/D layout (m89): col = lane&15, row = (lane>>4)*4 + reg
    const int colb = lane & 15, rowb = (lane >> 4) * 4;
    float Trow[16];
    if (active) {
        #pragma unroll
        for (int z = 0; z < 16; ++z)
            Trow[z] = rowT[(b << 12) + Q0 + wm + (z >> 2) * 16 + rowb + (z & 3)];
    }

    if (tid < 128) cntL[tid] = 0;
    __syncthreads();

    if (active) {
        #pragma unroll
        for (int i = 0; i < 4; ++i)
            #pragma unroll
            for (int r = 0; r < 4; ++r) {
                const int row = wm + i * 16 + rowb + r;       // block-relative
                const int grow = Q0 + row;
                const float Tr = Trow[i * 4 + r];
                #pragma unroll
                for (int j = 0; j < 4; ++j) {
                    float val = acc[i][j][r];
                    int col = S0 + wn + j * 16 + colb;
                    if (val >= Tr && col <= grow) atomicAdd(&cntL[row], 1);
                }
            }
    }
    __syncthreads();

    if (tid < 128) {
        int c = cntL[tid];
        baseL[tid] = c ? atomicAdd(&cntG[((b << 12) + Q0 + tid) * CPAD], c) : 0;
        cntL[tid] = 0;
    }
    __syncthreads();

    if (active) {
        #pragma unroll
        for (int i = 0; i < 4; ++i)
            #pragma unroll
            for (int r = 0; r < 4; ++r) {
                const int row = wm + i * 16 + rowb + r;
                const int grow = Q0 + row;
                const float Tr = Trow[i * 4 + r];
                const size_t segbase = (size_t)((b << 12) + grow) * ch;
                #pragma unroll
                for (int j = 0; j < 4; ++j) {
                    float val = acc[i][j][r];
                    int col = S0 + wn + j * 16 + colb;
                    if (val >= Tr && col <= grow) {
                        int p = atomicAdd(&cntL[row], 1) + baseL[row];
                        if (p < ch)
                            cand[segbase + p] =
                                ((unsigned long long)fmap(val) << 32) | (unsigned)(SEQ - col);
                    }
                }
            }
    }
}

// ---------- candidate select: one wave per row, exact rank + V gather ----------
__launch_bounds__(256)
__global__ void select_cand(const unsigned long long* __restrict__ cand,
                            const int* __restrict__ cntG,
                            const float* __restrict__ v,
                            float* __restrict__ out, int ch) {
    __shared__ unsigned long long bufK[4][256];
    __shared__ float sW[4][TOPK];
    __shared__ int   sI[4][TOPK];

    const int w = threadIdx.x >> 6, lane = threadIdx.x & 63;
    const int t = blockIdx.x * 4 + w, b = blockIdx.y;
    const int rb = (b << 12) + t;
    int C = cntG[rb * CPAD];
    if (C > ch) C = ch;
    const unsigned long long* seg = cand + (size_t)rb * ch;

    unsigned um = 0u;
    for (int c0 = lane; c0 < C; c0 += 64) {
        unsigned long long kk = seg[c0];
        bufK[w][c0] = kk;
        unsigned hi = (unsigned)(kk >> 32);
        um = hi > um ? hi : um;
    }
    um = wave_umax(um);
    const float M = finv(um);

    sW[w][lane] = 0.f; sI[w][lane] = 0;
    for (int c0 = lane; c0 < C; c0 += 64) {
        unsigned long long kc = bufK[w][c0];
        int r = 0;
        for (int j = 0; j < C; ++j) r += (bufK[w][j] > kc);
        if (r < TOPK) {
            sW[w][r] = expf(finv((unsigned)(kc >> 32)) - M);
            sI[w][r] = SEQ - (int)(kc & 0xFFFFFFFFu);
        }
    }

    float S = wave_fsum(sW[w][lane]);
    float inv = 1.f / S;

    const int sub = lane & 31, halfw = lane >> 5;
    f32x4 a4 = {0.f, 0.f, 0.f, 0.f};
    for (int j2 = halfw; j2 < TOPK; j2 += 2) {
        float wj = sW[w][j2];
        const float4* vr = (const float4*)(v + ((size_t)(b << 12) + sI[w][j2]) * DM) + sub;
        float4 vv = *vr;
        a4.x += wj * vv.x; a4.y += wj * vv.y; a4.z += wj * vv.z; a4.w += wj * vv.w;
    }
    a4.x += __shfl_xor(a4.x, 32);
    a4.y += __shfl_xor(a4.y, 32);
    a4.z += __shfl_xor(a4.z, 32);
    a4.w += __shfl_xor(a4.w, 32);
    if (halfw == 0) {
        float4 o4;
        o4.x = a4.x * inv; o4.y = a4.y * inv; o4.z = a4.z * inv; o4.w = a4.w * inv;
        *((float4*)(out + ((size_t)(b << 12) + t) * DM) + sub) = o4;
    }
}

// ============ chunked backup path (round-6 proven, direct-global) ============
__launch_bounds__(256, 2)
__global__ void logits_mfma(const unsigned short* __restrict__ qh, const unsigned short* __restrict__ qm,
                            const unsigned short* __restrict__ ql, const unsigned short* __restrict__ kh,
                            const unsigned short* __restrict__ km, const unsigned short* __restrict__ kl,
                            float* __restrict__ lg, int r0, int m, int stride) {
    const int st = blockIdx.x, qt = blockIdx.y, b = blockIdx.z;
    const int Q0 = r0 + qt * 128, S0 = st * 128;
    if (S0 > Q0 + 127) return;
    const int tid = threadIdx.x, lane = tid & 63, w = tid >> 6;
    const int wm = (w >> 1) * 64, wn = (w & 1) * 64;
    if (S0 + wn > Q0 + wm + 63) return;

    const int rA = Q0 + wm + (lane & 15);
    const int rB = S0 + wn + (lane & 15);
    const int dc = (lane >> 4) * 8;

    f32x4 acc[4][4] = {};
    #pragma unroll
    for (int kk = 0; kk < 4; ++kk) {
        const int doff = kk * 32 + dc;
        bf16x8 Ah[4], Am[4], Al[4], Bh[4], Bm[4], Bl[4];
        #pragma unroll
        for (int i = 0; i < 4; ++i) {
            size_t qoff = ((size_t)b * SEQ + rA + i * 16) * DM + doff;
            Ah[i] = *(const bf16x8*)(qh + qoff);
            Am[i] = *(const bf16x8*)(qm + qoff);
            Al[i] = *(const bf16x8*)(ql + qoff);
            size_t koff = ((size_t)b * SEQ + rB + i * 16) * DM + doff;
            Bh[i] = *(const bf16x8*)(kh + koff);
            Bm[i] = *(const bf16x8*)(km + koff);
            Bl[i] = *(const bf16x8*)(kl + koff);
        }
        #pragma unroll
        for (int i = 0; i < 4; ++i)
            #pragma unroll
            for (int j = 0; j < 4; ++j) {
                f32x4 c = acc[i][j];
                c = __builtin_amdgcn_mfma_f32_16x16x32_bf16(Ah[i], Bh[j], c, 0, 0, 0);
                c = __builtin_amdgcn_mfma_f32_16x16x32_bf16(Ah[i], Bm[j], c, 0, 0, 0);
                c = __builtin_amdgcn_mfma_f32_16x16x32_bf16(Am[i], Bh[j], c, 0, 0, 0);
                c = __builtin_amdgcn_mfma_f32_16x16x32_bf16(Ah[i], Bl[j], c, 0, 0, 0);
                c = __builtin_amdgcn_mfma_f32_16x16x32_bf16(Al[i], Bh[j], c, 0, 0, 0);
                c = __builtin_amdgcn_mfma_f32_16x16x32_bf16(Am[i], Bm[j], c, 0, 0, 0);
                acc[i][j] = c;
            }
    }

    const int colb = lane & 15, rowb = (lane >> 4) * 4;
    #pragma unroll
    for (int i = 0; i < 4; ++i) {
        #pragma unroll
        for (int r = 0; r < 4; ++r) {
            int qrow = Q0 + wm + i * 16 + rowb + r;
            size_t base = ((size_t)(b * m + (qrow - r0))) * stride;
            #pragma unroll
            for (int j = 0; j < 4; ++j) {
                int col = S0 + wn + j * 16 + colb;
                if (col <= qrow) lg[base + col] = acc[i][j][r];
            }
        }
    }
}

__launch_bounds__(256)
__global__ void select_out2(const float* __restrict__ lg, const float* __restrict__ v,
                            float* __restrict__ out, int r0, int m, int stride) {
    __shared__ unsigned long long bufK[4][CAP];
    __shared__ float sW[4][TOPK];
    __shared__ int   sI[4][TOPK];
    __shared__ int   cnt[4];

    const int w = threadIdx.x >> 6, lane = threadIdx.x & 63;
    const int x = blockIdx.x * 4 + w, b = blockIdx.y;
    if (x >= m) return;
    const int t = r0 + x, n = t + 1;
    const float* row = lg + ((size_t)(b * m + x)) * stride;
    const float4* row4 = (const float4*)row;
    const int nv4 = n >> 2, rem = n & 3;

    if (n <= TOPK) {
        float val = (lane < n) ? row[lane] : -3.0e38f;
        float M = wave_fmax(val);
        float wgt = (lane < n) ? expf(val - M) : 0.f;
        float S = wave_fsum(wgt);
        sW[w][lane] = wgt;
        float inv = 1.f / S;
        float a0 = 0.f, a1 = 0.f;
        for (int j = 0; j < n; ++j) {
            float wj = sW[w][j];
            size_t base = ((size_t)b * SEQ + j) * DM;
            a0 += wj * v[base + lane];
            a1 += wj * v[base + 64 + lane];
        }
        size_t ob = ((size_t)b * SEQ + t) * DM;
        out[ob + lane] = a0 * inv;
        out[ob + 64 + lane] = a1 * inv;
        return;
    }

    float T, zt = 0.f;
    if (n <= CAP - 32) T = -3.0e38f;
    else { zt = ztail(128.f / (float)n); T = zt; }

    float Tlo = -3.3e38f, Thi = 3.3e38f;
    int C = 0;
    unsigned um = 0u;
    for (int it = 0; it < 12; ++it) {
        if (lane == 0) cnt[w] = 0;
        unsigned lm = 0u;
        for (int i = lane; i < nv4; i += 64) {
            float4 r4 = row4[i];
            int s = i << 2;
            if (r4.x >= T) { unsigned u = fmap(r4.x); lm = u > lm ? u : lm; int p = atomicAdd(&cnt[w], 1); if (p < CAP) bufK[w][p] = ((unsigned long long)u << 32) | (unsigned)(SEQ - s); }
            if (r4.y >= T) { unsigned u = fmap(r4.y); lm = u > lm ? u : lm; int p = atomicAdd(&cnt[w], 1); if (p < CAP) bufK[w][p] = ((unsigned long long)u << 32) | (unsigned)(SEQ - (s + 1)); }
            if (r4.z >= T) { unsigned u = fmap(r4.z); lm = u > lm ? u : lm; int p = atomicAdd(&cnt[w], 1); if (p < CAP) bufK[w][p] = ((unsigned long long)u << 32) | (unsigned)(SEQ - (s + 2)); }
            if (r4.w >= T) { unsigned u = fmap(r4.w); lm = u > lm ? u : lm; int p = atomicAdd(&cnt[w], 1); if (p < CAP) bufK[w][p] = ((unsigned long long)u << 32) | (unsigned)(SEQ - (s + 3)); }
        }
        if (lane < rem) {
            float val = row[nv4 * 4 + lane];
            if (val >= T) { unsigned u = fmap(val); lm = u > lm ? u : lm; int p = atomicAdd(&cnt[w], 1); if (p < CAP) bufK[w][p] = ((unsigned long long)u << 32) | (unsigned)(SEQ - (nv4 * 4 + lane)); }
        }
        um = wave_umax(lm);
        C = cnt[w];
        if (C >= TOPK && C <= CAP) break;
        if (C < TOPK) Thi = fminf(Thi, T); else Tlo = fmaxf(Tlo, T);
        float Tn; bool okc = false;
        float phat = (float)(C < 1 ? 1 : C) / (float)n;
        if (phat < 0.45f && T > 0.05f) {
            float zh = ztail(phat);
            if (zh > 0.05f) { Tn = T * (zt / zh); okc = true; }
        }
        if (!okc || !(Tn > Tlo && Tn < Thi)) {
            if (Tlo > -3.2e38f && Thi < 3.2e38f) Tn = 0.5f * (Tlo + Thi);
            else if (C < TOPK)                   Tn = T - 0.5f;
            else                                 Tn = T + 0.4f;
        }
        T = Tn;
    }
    const float M = finv(um);
    int Cw = C; if (Cw > CAP) Cw = CAP;

    sW[w][lane] = 0.f; sI[w][lane] = 0;
    for (int c0 = lane; c0 < Cw; c0 += 64) {
        unsigned long long kc = bufK[w][c0];
        int r = 0;
        for (int j = 0; j < Cw; ++j) r += (bufK[w][j] > kc);
        if (r < TOPK) {
            sW[w][r] = expf(finv((unsigned)(kc >> 32)) - M);
            sI[w][r] = SEQ - (int)(kc & 0xFFFFFFFFu);
        }
    }
    float S = wave_fsum(sW[w][lane]);
    float inv = 1.f / S;

    const int sub = lane & 31, halfw = lane >> 5;
    f32x4 a4 = {0.f, 0.f, 0.f, 0.f};
    for (int j2 = halfw; j2 < TOPK; j2 += 2) {
        float wj = sW[w][j2];
        const float4* vr = (const float4*)(v + ((size_t)b * SEQ + sI[w][j2]) * DM) + sub;
        float4 vv = *vr;
        a4.x += wj * vv.x; a4.y += wj * vv.y; a4.z += wj * vv.z; a4.w += wj * vv.w;
    }
    a4.x += __shfl_xor(a4.x, 32);
    a4.y += __shfl_xor(a4.y, 32);
    a4.z += __shfl_xor(a4.z, 32);
    a4.w += __shfl_xor(a4.w, 32);
    if (halfw == 0) {
        float4 o4;
        o4.x = a4.x * inv; o4.y = a4.y * inv; o4.z = a4.z * inv; o4.w = a4.w * inv;
        *((float4*)(out + ((size_t)b * SEQ + t) * DM) + sub) = o4;
    }
}

// ---------- small-ws fallback: fp32 rope + round-2 kernel ----------
__global__ void rope_prep(const float* __restrict__ q, const float* __restrict__ k,
                          float* __restrict__ rq, float* __restrict__ rk) {
    int idx = blockIdx.x * blockDim.x + threadIdx.x;
    const int total = BATCH * SEQ * (DM / 2);
    if (idx >= total) return;
    int i   = idx & 63;
    int pos = (idx >> 6) & (SEQ - 1);
    int b   = idx >> 18;
    float dv  = powf(10000.0f, (float)(2 * i) / (float)DM);
    float ang = (float)pos / dv;
    float sn, cs;
    sincosf(ang, &sn, &cs);
    size_t base = ((size_t)b * SEQ + pos) * DM + 2 * i;
    float qe = q[base], qo = q[base + 1];
    float ke = k[base], ko = k[base + 1];
    rq[base]     = qe * cs - qo * sn;
    rq[base + 1] = qe * sn + qo * cs;
    rk[base]     = ke * cs - ko * sn;
    rk[base + 1] = ke * sn + ko * cs;
}

__launch_bounds__(256)
__global__ void topk_attn(const float* __restrict__ rq, const float* __restrict__ rk,
                          const float* __restrict__ v, float* __restrict__ out) {
    __shared__ unsigned umap[SEQ];
    __shared__ float    qs[DM];
    __shared__ int      selIdx[TOPK];
    __shared__ float    selW[TOPK];
    __shared__ int      cnt;
    __shared__ float    redf[4];
    __shared__ int      redi[4];
    __shared__ float    sMax, sSum;

    const int t   = blockIdx.x & (SEQ - 1);
    const int b   = blockIdx.x >> 12;
    const int tid = threadIdx.x;
    const int lane = tid & 63, wid = tid >> 6;
    const int n = t + 1;

    if (tid < DM) qs[tid] = rq[((size_t)b * SEQ + t) * DM + tid];
    if (tid == 0) cnt = 0;
    __syncthreads();

    float lmax = -INFINITY;
    for (int s = tid; s < n; s += 256) {
        const float4* kr = (const float4*)(rk + ((size_t)b * SEQ + s) * DM);
        const float4* qr = (const float4*)qs;
        float acc = 0.f;
        #pragma unroll
        for (int d = 0; d < DM / 4; ++d) {
            float4 kv = kr[d]; float4 qv = qr[d];
            acc += kv.x * qv.x + kv.y * qv.y + kv.z * qv.z + kv.w * qv.w;
        }
        float lgv = acc * SCALE;
        umap[s] = fmap(lgv);
        lmax = fmaxf(lmax, lgv);
    }
    #pragma unroll
    for (int off = 32; off; off >>= 1) lmax = fmaxf(lmax, __shfl_down(lmax, off));
    if (lane == 0) redf[wid] = lmax;
    __syncthreads();
    if (tid == 0) sMax = fmaxf(fmaxf(redf[0], redf[1]), fmaxf(redf[2], redf[3]));
    __syncthreads();
    const float M = sMax;

    const int K = (n < TOPK) ? n : TOPK;
    unsigned thr = 0u;
    if (n > TOPK) {
        unsigned long long lo = 0ull, hi = (unsigned long long)fmap(M);
        while (lo < hi) {
            unsigned long long mid = (lo + hi + 1ull) >> 1;
            unsigned m32 = (unsigned)mid;
            int c = 0;
            for (int s = tid; s < n; s += 256) c += (umap[s] >= m32) ? 1 : 0;
            #pragma unroll
            for (int off = 32; off; off >>= 1) c += __shfl_down(c, off);
            if (lane == 0) redi[wid] = c;
            __syncthreads();
            int tot = redi[0] + redi[1] + redi[2] + redi[3];
            __syncthreads();
            if (tot >= K) lo = mid; else hi = mid - 1ull;
        }
        thr = (unsigned)lo;
    }

    for (int s = tid; s < n; s += 256) {
        if (umap[s] > thr) {
            int p = atomicAdd(&cnt, 1);
            if (p < TOPK) { selIdx[p] = s; selW[p] = expf(finv(umap[s]) - M); }
        }
    }
    __syncthreads();
    for (int s = tid; s < n; s += 256) {
        if (umap[s] == thr) {
            int p = atomicAdd(&cnt, 1);
            if (p < TOPK) { selIdx[p] = s; selW[p] = expf(finv(umap[s]) - M); }
        }
    }
    __syncthreads();
    const int nsel = (cnt < TOPK) ? cnt : TOPK;

    if (tid < 64) {
        float w = (tid < nsel) ? selW[tid] : 0.f;
        #pragma unroll
        for (int off = 32; off; off >>= 1) w += __shfl_down(w, off);
        if (tid == 0) sSum = w;
    }
    __syncthreads();
    const float inv = 1.0f / sSum;

    if (tid < DM) {
        float a = 0.f;
        for (int j = 0; j < nsel; ++j)
            a += selW[j] * v[((size_t)b * SEQ + selIdx[j]) * DM + tid];
        out[((size_t)b * SEQ + t) * DM + tid] = a * inv;
    }
}

extern "C" void kernel_launch(void* const* d_in, const int* in_sizes, int n_in,
                              void* d_out, int out_size, void* d_ws, size_t ws_size,
                              hipStream_t stream) {
    const float* q = (const float*)d_in[0];
    const float* k = (const float*)d_in[1];
    const float* v = (const float*)d_in[2];
    float* out = (float*)d_out;

    const size_t plane = (size_t)BATCH * SEQ * DM;
    const size_t planesB = 6 * plane * sizeof(unsigned short);        // ~25 MB
    const size_t rowTB   = (size_t)BATCH * SEQ * sizeof(float);       // 64 KB
    const size_t cntB    = (size_t)BATCH * SEQ * CPAD * sizeof(int);  // 1 MB (padded)
    const int total = BATCH * SEQ * (DM / 2);

    // fused tiers: CH=256 (~60 MB) or CH=192 (~51 MB)
    int ch = 0;
    {
        const size_t need256 = planesB + rowTB + (size_t)BATCH * SEQ * 256 * 8 + cntB;
        const size_t need192 = planesB + rowTB + (size_t)BATCH * SEQ * 192 * 8 + cntB;
        if (ws_size >= need256) ch = 256;
        else if (ws_size >= need192) ch = 192;
    }

    if (ch > 0) {
        const size_t candB = (size_t)BATCH * SEQ * ch * 8;
        unsigned short* qh = (unsigned short*)d_ws;
        unsigned short* qm = qh + plane;
        unsigned short* ql = qm + plane;
        unsigned short* kh = ql + plane;
        unsigned short* km = kh + plane;
        unsigned short* kl = km + plane;
        float* rowT = (float*)((char*)d_ws + planesB);
        unsigned long long* cand = (unsigned long long*)((char*)d_ws + planesB + rowTB);
        int* cntG = (int*)((char*)d_ws + planesB + rowTB + candB);

        hipMemsetAsync(cntG, 0, cntB, stream);
        hipLaunchKernelGGL(rope_decomp, dim3((total + 255) / 256), dim3(256), 0, stream,
                           q, k, qh, qm, ql, kh, km, kl, rowT, ch, CT);
        hipLaunchKernelGGL(topk_fused, dim3(SEQ / 128, SEQ / 128, BATCH), dim3(256), 0, stream,
                           qh, qm, ql, kh, km, kl, rowT, cand, cntG, ch);
        hipLaunchKernelGGL(select_cand, dim3(SEQ / 4, BATCH), dim3(256), 0, stream,
                           cand, cntG, v, out, ch);
        return;
    }

    // chunked backup: planes + rowT + lgbuf chunks
    long long Wb = (long long)ws_size - (long long)(planesB + rowTB);
    int cr0[64], cm[64], nch = 0;
    bool okc = (Wb > 0);
    int r0 = 0;
    while (okc && r0 < SEQ) {
        int m = SEQ - r0;
        while (m >= 128) {
            long long stride = ((r0 + m + 127) / 128) * 128;
            long long bytes = (long long)BATCH * m * stride * 4;
            if (bytes <= Wb) break;
            m -= 128;
        }
        if (m < 128 || nch >= 64) { okc = false; break; }
        cr0[nch] = r0; cm[nch] = m; ++nch;
        r0 += m;
    }

    if (!okc) {
        float* rq = (float*)d_ws;
        float* rk = rq + plane;
        hipLaunchKernelGGL(rope_prep, dim3((total + 255) / 256), dim3(256), 0, stream,
                           q, k, rq, rk);
        hipLaunchKernelGGL(topk_attn, dim3(BATCH * SEQ), dim3(256), 0, stream,
                           rq, rk, v, out);
        return;
    }

    unsigned short* qh = (unsigned short*)d_ws;
    unsigned short* qm = qh + plane;
    unsigned short* ql = qm + plane;
    unsigned short* kh = ql + plane;
    unsigned short* km = kh + plane;
    unsigned short* kl = km + plane;
    float* rowT = (float*)((char*)d_ws + planesB);
    float* lgbuf = (float*)((char*)d_ws + planesB + rowTB);

    hipLaunchKernelGGL(rope_decomp, dim3((total + 255) / 256), dim3(256), 0, stream,
                       q, k, qh, qm, ql, kh, km, kl, rowT, CAP, CT);

    for (int c = 0; c < nch; ++c) {
        const int R0 = cr0[c], M = cm[c];
        const int stride = ((R0 + M + 127) / 128) * 128;
        dim3 g1((R0 + M + 127) / 128, M / 128, BATCH);
        hipLaunchKernelGGL(logits_mfma, g1, dim3(256), 0, stream,
                           qh, qm, ql, kh, km, kl, lgbuf, R0, M, stride);
        dim3 g2((M + 3) / 4, BATCH);
        hipLaunchKernelGGL(select_out2, g2, dim3(256), 0, stream,
                           lgbuf, v, out, R0, M, stride);
    }
}

// Round 13
// 242.825 us; speedup vs baseline: 1.4024x; 1.4024x over previous
//
#include <hip/hip_runtime.h>
#include <math.h>

#define BATCH 4
#define SEQ   4096
#define DM    128
#define TOPK  64
#define SCALE 0.08838834764831845f   // 1/sqrt(128)
#define CAP   384                    // candidate buffer per row (select)

typedef short bf16x8 __attribute__((ext_vector_type(8)));
typedef float f32x4  __attribute__((ext_vector_type(4)));

// ---- bf16 helpers (RNE) ----
__device__ __forceinline__ unsigned short f2bf(float x) {
    unsigned u = __float_as_uint(x);
    u += 0x7FFFu + ((u >> 16) & 1u);
    return (unsigned short)(u >> 16);
}
__device__ __forceinline__ float bf2f(unsigned short h) {
    return __uint_as_float(((unsigned)h) << 16);
}
__device__ __forceinline__ void split3(float x, unsigned short& h,
                                       unsigned short& md, unsigned short& l) {
    h = f2bf(x);
    float r1 = x - bf2f(h);
    md = f2bf(r1);
    float r2 = r1 - bf2f(md);
    l = f2bf(r2);
}

__device__ __forceinline__ unsigned fmap(float f) {
    unsigned u = __float_as_uint(f);
    return (u & 0x80000000u) ? ~u : (u | 0x80000000u);
}
__device__ __forceinline__ float finv(unsigned u) {
    return (u & 0x80000000u) ? __uint_as_float(u & 0x7FFFFFFFu) : __uint_as_float(~u);
}
__device__ __forceinline__ float wave_fmax(float v) {
    #pragma unroll
    for (int m = 32; m; m >>= 1) v = fmaxf(v, __shfl_xor(v, m));
    return v;
}
__device__ __forceinline__ float wave_fsum(float v) {
    #pragma unroll
    for (int m = 32; m; m >>= 1) v += __shfl_xor(v, m);
    return v;
}
__device__ __forceinline__ unsigned wave_umax(unsigned v) {
    #pragma unroll
    for (int m = 32; m; m >>= 1) { unsigned o = __shfl_xor(v, m); v = (o > v) ? o : v; }
    return v;
}

// upper-tail normal quantile z with P(X > z) = p (Hastings, symmetric)
__device__ __forceinline__ float ztail(float p) {
    float pp = (p <= 0.5f) ? p : (1.f - p);
    float tt = sqrtf(-2.f * logf(pp));
    float z = tt - (2.30753f + 0.27061f * tt) / (1.f + 0.99229f * tt + 0.04481f * tt * tt);
    return (p <= 0.5f) ? z : -z;
}

// ---------- RoPE + 3-way bf16 decomposition ----------
__global__ void rope_decomp(const float* __restrict__ q, const float* __restrict__ k,
                            unsigned short* __restrict__ qh, unsigned short* __restrict__ qm,
                            unsigned short* __restrict__ ql, unsigned short* __restrict__ kh,
                            unsigned short* __restrict__ km, unsigned short* __restrict__ kl) {
    int idx = blockIdx.x * blockDim.x + threadIdx.x;
    const int total = BATCH * SEQ * (DM / 2);
    if (idx >= total) return;
    int i   = idx & 63;
    int pos = (idx >> 6) & (SEQ - 1);
    int b   = idx >> 18;
    float dv  = powf(10000.0f, (float)(2 * i) / (float)DM);
    float ang = (float)pos / dv;
    float sn, cs;
    sincosf(ang, &sn, &cs);
    size_t base = ((size_t)b * SEQ + pos) * DM + 2 * i;
    float qe = q[base], qo = q[base + 1];
    float ke = k[base], ko = k[base + 1];
    float q0 = (qe * cs - qo * sn) * SCALE, q1 = (qe * sn + qo * cs) * SCALE;
    float k0 = ke * cs - ko * sn,          k1 = ke * sn + ko * cs;
    unsigned short h, m2, l;
    split3(q0, h, m2, l); qh[base] = h;     qm[base] = m2;     ql[base] = l;
    split3(q1, h, m2, l); qh[base + 1] = h; qm[base + 1] = m2; ql[base + 1] = l;
    split3(k0, h, m2, l); kh[base] = h;     km[base] = m2;     kl[base] = l;
    split3(k1, h, m2, l); kh[base + 1] = h; km[base + 1] = m2; kl[base + 1] = l;
}

// ---------- Phase A: logits via bf16 MFMA, direct-global fragments ----------
// (round-5 proven: 106us dominant chunk, MfmaUtil 17%; faster than LDS-staged)
__launch_bounds__(256, 2)
__global__ void logits_mfma(const unsigned short* __restrict__ qh, const unsigned short* __restrict__ qm,
                            const unsigned short* __restrict__ ql, const unsigned short* __restrict__ kh,
                            const unsigned short* __restrict__ km, const unsigned short* __restrict__ kl,
                            float* __restrict__ lg, int r0, int m, int stride) {
    const int st = blockIdx.x, qt = blockIdx.y, b = blockIdx.z;
    const int Q0 = r0 + qt * 128, S0 = st * 128;
    if (S0 > Q0 + 127) return;
    const int tid = threadIdx.x, lane = tid & 63, w = tid >> 6;
    const int wm = (w >> 1) * 64, wn = (w & 1) * 64;
    if (S0 + wn > Q0 + wm + 63) return;            // wave fully masked

    const int rA = Q0 + wm + (lane & 15);
    const int rB = S0 + wn + (lane & 15);
    const int dc = (lane >> 4) * 8;

    f32x4 acc[4][4] = {};
    #pragma unroll
    for (int kk = 0; kk < 4; ++kk) {
        const int doff = kk * 32 + dc;
        bf16x8 Ah[4], Am[4], Al[4], Bh[4], Bm[4], Bl[4];
        #pragma unroll
        for (int i = 0; i < 4; ++i) {
            size_t qoff = ((size_t)b * SEQ + rA + i * 16) * DM + doff;
            Ah[i] = *(const bf16x8*)(qh + qoff);
            Am[i] = *(const bf16x8*)(qm + qoff);
            Al[i] = *(const bf16x8*)(ql + qoff);
            size_t koff = ((size_t)b * SEQ + rB + i * 16) * DM + doff;
            Bh[i] = *(const bf16x8*)(kh + koff);
            Bm[i] = *(const bf16x8*)(km + koff);
            Bl[i] = *(const bf16x8*)(kl + koff);
        }
        #pragma unroll
        for (int i = 0; i < 4; ++i)
            #pragma unroll
            for (int j = 0; j < 4; ++j) {
                f32x4 c = acc[i][j];
                c = __builtin_amdgcn_mfma_f32_16x16x32_bf16(Ah[i], Bh[j], c, 0, 0, 0);
                c = __builtin_amdgcn_mfma_f32_16x16x32_bf16(Ah[i], Bm[j], c, 0, 0, 0);
                c = __builtin_amdgcn_mfma_f32_16x16x32_bf16(Am[i], Bh[j], c, 0, 0, 0);
                c = __builtin_amdgcn_mfma_f32_16x16x32_bf16(Ah[i], Bl[j], c, 0, 0, 0);
                c = __builtin_amdgcn_mfma_f32_16x16x32_bf16(Al[i], Bh[j], c, 0, 0, 0);
                c = __builtin_amdgcn_mfma_f32_16x16x32_bf16(Am[i], Bm[j], c, 0, 0, 0);
                acc[i][j] = c;
            }
    }

    // C/D layout (m89-verified): col = lane&15, row = (lane>>4)*4 + reg
    const int colb = lane & 15, rowb = (lane >> 4) * 4;
    #pragma unroll
    for (int i = 0; i < 4; ++i) {
        #pragma unroll
        for (int r = 0; r < 4; ++r) {
            int qrow = Q0 + wm + i * 16 + rowb + r;
            size_t base = ((size_t)(b * m + (qrow - r0))) * stride;
            #pragma unroll
            for (int j = 0; j < 4; ++j) {
                int col = S0 + wn + j * 16 + colb;
                if (col <= qrow) lg[base + col] = acc[i][j][r];
            }
        }
    }
}

// ---------- Phase B: one WAVE per row; single-pass append + exact rank ----------
// (round-7 proven; ~65us for all 16K rows by subtraction)
__launch_bounds__(256)
__global__ void select_out2(const float* __restrict__ lg, const float* __restrict__ v,
                            float* __restrict__ out, int r0, int m, int stride) {
    __shared__ unsigned long long bufK[4][CAP];
    __shared__ float sW[4][TOPK];
    __shared__ int   sI[4][TOPK];
    __shared__ int   cnt[4];

    const int w = threadIdx.x >> 6, lane = threadIdx.x & 63;
    const int x = blockIdx.x * 4 + w, b = blockIdx.y;
    if (x >= m) return;
    const int t = r0 + x, n = t + 1;
    const float* row = lg + ((size_t)(b * m + x)) * stride;
    const float4* row4 = (const float4*)row;
    const int nv4 = n >> 2, rem = n & 3;

    if (n <= TOPK) {
        float val = (lane < n) ? row[lane] : -3.0e38f;
        float M = wave_fmax(val);
        float wgt = (lane < n) ? expf(val - M) : 0.f;
        float S = wave_fsum(wgt);
        sW[w][lane] = wgt;
        float inv = 1.f / S;
        float a0 = 0.f, a1 = 0.f;
        for (int j = 0; j < n; ++j) {
            float wj = sW[w][j];
            size_t base = ((size_t)b * SEQ + j) * DM;
            a0 += wj * v[base + lane];
            a1 += wj * v[base + 64 + lane];
        }
        size_t ob = ((size_t)b * SEQ + t) * DM;
        out[ob + lane] = a0 * inv;
        out[ob + 64 + lane] = a1 * inv;
        return;
    }

    // target quantile (used when n > CAP-32)
    float T, zt = 0.f;
    if (n <= CAP - 32) T = -3.0e38f;          // take all n (<= 352 <= CAP)
    else { zt = ztail(128.f / (float)n); T = zt; }

    // ---- optimistic single-pass append; rare retry with recalibrated T ----
    float Tlo = -3.3e38f, Thi = 3.3e38f;
    int C = 0;
    unsigned um = 0u;
    for (int it = 0; it < 12; ++it) {
        if (lane == 0) cnt[w] = 0;
        unsigned lm = 0u;
        for (int i = lane; i < nv4; i += 64) {
            float4 r4 = row4[i];
            int s = i << 2;
            if (r4.x >= T) { unsigned u = fmap(r4.x); lm = u > lm ? u : lm; int p = atomicAdd(&cnt[w], 1); if (p < CAP) bufK[w][p] = ((unsigned long long)u << 32) | (unsigned)(SEQ - s); }
            if (r4.y >= T) { unsigned u = fmap(r4.y); lm = u > lm ? u : lm; int p = atomicAdd(&cnt[w], 1); if (p < CAP) bufK[w][p] = ((unsigned long long)u << 32) | (unsigned)(SEQ - (s + 1)); }
            if (r4.z >= T) { unsigned u = fmap(r4.z); lm = u > lm ? u : lm; int p = atomicAdd(&cnt[w], 1); if (p < CAP) bufK[w][p] = ((unsigned long long)u << 32) | (unsigned)(SEQ - (s + 2)); }
            if (r4.w >= T) { unsigned u = fmap(r4.w); lm = u > lm ? u : lm; int p = atomicAdd(&cnt[w], 1); if (p < CAP) bufK[w][p] = ((unsigned long long)u << 32) | (unsigned)(SEQ - (s + 3)); }
        }
        if (lane < rem) {
            float val = row[nv4 * 4 + lane];
            if (val >= T) { unsigned u = fmap(val); lm = u > lm ? u : lm; int p = atomicAdd(&cnt[w], 1); if (p < CAP) bufK[w][p] = ((unsigned long long)u << 32) | (unsigned)(SEQ - (nv4 * 4 + lane)); }
        }
        um = wave_umax(lm);
        C = cnt[w];                    // same-wave LDS ordering
        if (C >= TOPK && C <= CAP) break;
        if (C < TOPK) Thi = fminf(Thi, T); else Tlo = fmaxf(Tlo, T);
        float Tn; bool okc = false;
        float phat = (float)(C < 1 ? 1 : C) / (float)n;
        if (phat < 0.45f && T > 0.05f) {
            float zh = ztail(phat);
            if (zh > 0.05f) { Tn = T * (zt / zh); okc = true; }
        }
        if (!okc || !(Tn > Tlo && Tn < Thi)) {
            if (Tlo > -3.2e38f && Thi < 3.2e38f) Tn = 0.5f * (Tlo + Thi);
            else if (C < TOPK)                   Tn = T - 0.5f;
            else                                 Tn = T + 0.4f;
        }
        T = Tn;
    }
    const float M = finv(um);
    int Cw = C; if (Cw > CAP) Cw = CAP;

    sW[w][lane] = 0.f; sI[w][lane] = 0;

    // ---- exact rank: descending key order == (value desc, index asc) ----
    for (int c0 = lane; c0 < Cw; c0 += 64) {
        unsigned long long kc = bufK[w][c0];
        int r = 0;
        for (int j = 0; j < Cw; ++j) r += (bufK[w][j] > kc);
        if (r < TOPK) {
            sW[w][r] = expf(finv((unsigned)(kc >> 32)) - M);
            sI[w][r] = SEQ - (int)(kc & 0xFFFFFFFFu);
        }
    }
    float S = wave_fsum(sW[w][lane]);
    float inv = 1.f / S;

    // ---- weighted V gather: float4, half-wave 0 = even sel, half 1 = odd ----
    const int sub = lane & 31, halfw = lane >> 5;
    f32x4 a4 = {0.f, 0.f, 0.f, 0.f};
    for (int j2 = halfw; j2 < TOPK; j2 += 2) {
        float wj = sW[w][j2];
        const float4* vr = (const float4*)(v + ((size_t)b * SEQ + sI[w][j2]) * DM) + sub;
        float4 vv = *vr;
        a4.x += wj * vv.x; a4.y += wj * vv.y; a4.z += wj * vv.z; a4.w += wj * vv.w;
    }
    a4.x += __shfl_xor(a4.x, 32);
    a4.y += __shfl_xor(a4.y, 32);
    a4.z += __shfl_xor(a4.z, 32);
    a4.w += __shfl_xor(a4.w, 32);
    if (halfw == 0) {
        float4 o4;
        o4.x = a4.x * inv; o4.y = a4.y * inv; o4.z = a4.z * inv; o4.w = a4.w * inv;
        *((float4*)(out + ((size_t)b * SEQ + t) * DM) + sub) = o4;
    }
}

// ---------- small-ws fallback: fp32 rope + round-2 kernel ----------
__global__ void rope_prep(const float* __restrict__ q, const float* __restrict__ k,
                          float* __restrict__ rq, float* __restrict__ rk) {
    int idx = blockIdx.x * blockDim.x + threadIdx.x;
    const int total = BATCH * SEQ * (DM / 2);
    if (idx >= total) return;
    int i   = idx & 63;
    int pos = (idx >> 6) & (SEQ - 1);
    int b   = idx >> 18;
    float dv  = powf(10000.0f, (float)(2 * i) / (float)DM);
    float ang = (float)pos / dv;
    float sn, cs;
    sincosf(ang, &sn, &cs);
    size_t base = ((size_t)b * SEQ + pos) * DM + 2 * i;
    float qe = q[base], qo = q[base + 1];
    float ke = k[base], ko = k[base + 1];
    rq[base]     = qe * cs - qo * sn;
    rq[base + 1] = qe * sn + qo * cs;
    rk[base]     = ke * cs - ko * sn;
    rk[base + 1] = ke * sn + ko * cs;
}

__launch_bounds__(256)
__global__ void topk_attn(const float* __restrict__ rq, const float* __restrict__ rk,
                          const float* __restrict__ v, float* __restrict__ out) {
    __shared__ unsigned umap[SEQ];
    __shared__ float    qs[DM];
    __shared__ int      selIdx[TOPK];
    __shared__ float    selW[TOPK];
    __shared__ int      cnt;
    __shared__ float    redf[4];
    __shared__ int      redi[4];
    __shared__ float    sMax, sSum;

    const int t   = blockIdx.x & (SEQ - 1);
    const int b   = blockIdx.x >> 12;
    const int tid = threadIdx.x;
    const int lane = tid & 63, wid = tid >> 6;
    const int n = t + 1;

    if (tid < DM) qs[tid] = rq[((size_t)b * SEQ + t) * DM + tid];
    if (tid == 0) cnt = 0;
    __syncthreads();

    float lmax = -INFINITY;
    for (int s = tid; s < n; s += 256) {
        const float4* kr = (const float4*)(rk + ((size_t)b * SEQ + s) * DM);
        const float4* qr = (const float4*)qs;
        float acc = 0.f;
        #pragma unroll
        for (int d = 0; d < DM / 4; ++d) {
            float4 kv = kr[d]; float4 qv = qr[d];
            acc += kv.x * qv.x + kv.y * qv.y + kv.z * qv.z + kv.w * qv.w;
        }
        float lgv = acc * SCALE;
        umap[s] = fmap(lgv);
        lmax = fmaxf(lmax, lgv);
    }
    #pragma unroll
    for (int off = 32; off; off >>= 1) lmax = fmaxf(lmax, __shfl_down(lmax, off));
    if (lane == 0) redf[wid] = lmax;
    __syncthreads();
    if (tid == 0) sMax = fmaxf(fmaxf(redf[0], redf[1]), fmaxf(redf[2], redf[3]));
    __syncthreads();
    const float M = sMax;

    const int K = (n < TOPK) ? n : TOPK;
    unsigned thr = 0u;
    if (n > TOPK) {
        unsigned long long lo = 0ull, hi = (unsigned long long)fmap(M);
        while (lo < hi) {
            unsigned long long mid = (lo + hi + 1ull) >> 1;
            unsigned m32 = (unsigned)mid;
            int c = 0;
            for (int s = tid; s < n; s += 256) c += (umap[s] >= m32) ? 1 : 0;
            #pragma unroll
            for (int off = 32; off; off >>= 1) c += __shfl_down(c, off);
            if (lane == 0) redi[wid] = c;
            __syncthreads();
            int tot = redi[0] + redi[1] + redi[2] + redi[3];
            __syncthreads();
            if (tot >= K) lo = mid; else hi = mid - 1ull;
        }
        thr = (unsigned)lo;
    }

    for (int s = tid; s < n; s += 256) {
        if (umap[s] > thr) {
            int p = atomicAdd(&cnt, 1);
            if (p < TOPK) { selIdx[p] = s; selW[p] = expf(finv(umap[s]) - M); }
        }
    }
    __syncthreads();
    for (int s = tid; s < n; s += 256) {
        if (umap[s] == thr) {
            int p = atomicAdd(&cnt, 1);
            if (p < TOPK) { selIdx[p] = s; selW[p] = expf(finv(umap[s]) - M); }
        }
    }
    __syncthreads();
    const int nsel = (cnt < TOPK) ? cnt : TOPK;

    if (tid < 64) {
        float w = (tid < nsel) ? selW[tid] : 0.f;
        #pragma unroll
        for (int off = 32; off; off >>= 1) w += __shfl_down(w, off);
        if (tid == 0) sSum = w;
    }
    __syncthreads();
    const float inv = 1.0f / sSum;

    if (tid < DM) {
        float a = 0.f;
        for (int j = 0; j < nsel; ++j)
            a += selW[j] * v[((size_t)b * SEQ + selIdx[j]) * DM + tid];
        out[((size_t)b * SEQ + t) * DM + tid] = a * inv;
    }
}

extern "C" void kernel_launch(void* const* d_in, const int* in_sizes, int n_in,
                              void* d_out, int out_size, void* d_ws, size_t ws_size,
                              hipStream_t stream) {
    const float* q = (const float*)d_in[0];
    const float* k = (const float*)d_in[1];
    const float* v = (const float*)d_in[2];
    float* out = (float*)d_out;

    const size_t plane = (size_t)BATCH * SEQ * DM;
    const size_t planesB = 6 * plane * sizeof(unsigned short);   // ~25 MB
    const int total = BATCH * SEQ * (DM / 2);

    // plan 128-granular query-row chunks; greedy max fit (no cap — round-7 lesson)
    long long Wb = (long long)ws_size - (long long)planesB;
    int cr0[64], cm[64], nch = 0;
    bool okc = (Wb > 0);
    int r0 = 0;
    while (okc && r0 < SEQ) {
        int m = SEQ - r0;
        while (m >= 128) {
            long long stride = ((r0 + m + 127) / 128) * 128;
            long long bytes = (long long)BATCH * m * stride * 4;
            if (bytes <= Wb) break;
            m -= 128;
        }
        if (m < 128 || nch >= 64) { okc = false; break; }
        cr0[nch] = r0; cm[nch] = m; ++nch;
        r0 += m;
    }

    if (!okc) {   // small-ws fallback: fp32 rope + round-2 kernel (needs 16 MB)
        float* rq = (float*)d_ws;
        float* rk = rq + plane;
        hipLaunchKernelGGL(rope_prep, dim3((total + 255) / 256), dim3(256), 0, stream,
                           q, k, rq, rk);
        hipLaunchKernelGGL(topk_attn, dim3(BATCH * SEQ), dim3(256), 0, stream,
                           rq, rk, v, out);
        return;
    }

    unsigned short* qh = (unsigned short*)d_ws;
    unsigned short* qm = qh + plane;
    unsigned short* ql = qm + plane;
    unsigned short* kh = ql + plane;
    unsigned short* km = kh + plane;
    unsigned short* kl = km + plane;
    float* lgbuf = (float*)((char*)d_ws + planesB);

    hipLaunchKernelGGL(rope_decomp, dim3((total + 255) / 256), dim3(256), 0, stream,
                       q, k, qh, qm, ql, kh, km, kl);

    for (int c = 0; c < nch; ++c) {
        const int R0 = cr0[c], M = cm[c];
        const int stride = ((R0 + M + 127) / 128) * 128;
        dim3 g1((R0 + M + 127) / 128, M / 128, BATCH);
        hipLaunchKernelGGL(logits_mfma, g1, dim3(256), 0, stream,
                           qh, qm, ql, kh, km, kl, lgbuf, R0, M, stride);
        dim3 g2((M + 3) / 4, BATCH);
        hipLaunchKernelGGL(select_out2, g2, dim3(256), 0, stream,
                           lgbuf, v, out, R0, M, stride);
    }
}